// Round 4
// baseline (480.266 us; speedup 1.0000x reference)
//
#include <hip/hip_runtime.h>
#include <hip/hip_bf16.h>
#include <cmath>

typedef __bf16 bf16x8 __attribute__((ext_vector_type(8)));
typedef __bf16 bf16x4 __attribute__((ext_vector_type(4)));
typedef float f32x4 __attribute__((ext_vector_type(4)));

#define GLOBAL_AS __attribute__((address_space(1)))
#define LDS_AS __attribute__((address_space(3)))

__device__ __forceinline__ void async_copy16(const void* g, void* l) {
    __builtin_amdgcn_global_load_lds((const GLOBAL_AS void*)g, (LDS_AS void*)l, 16, 0, 0);
}

// ---------------------------------------------------------------------------
// SEQ_idxes may be int64 or int32. As int32 words, int64 layout =
// [f0_lo, f0_hi(=0), ...]; int32 layout = [f0, s0(>=2049), ...]. seq[1]==0 <=> int64.
__device__ inline int get_first(const int* __restrict__ seq, int b) {
    int stride = (seq[1] == 0) ? 4 : 2;
    return seq[b * stride];
}

// T1 XCD swizzle (bijective when nwg % 8 == 0): dispatch-slot order is HW
// round-robin over 8 XCDs; remap so slots on one XCD get CONSECUTIVE work
// items (x-consecutive blocks share the B-panel -> panel becomes L2-resident
// on that XCD instead of replicated 8x).
__device__ inline void xcd_swizzle(int& bx, int& by, int& bz) {
    int gx = gridDim.x, gy = gridDim.y;
    int nwg = gx * gy * (int)gridDim.z;
    int flat = bx + gx * (by + gy * bz);
    int q = nwg >> 3;
    flat = (flat & 7) * q + (flat >> 3);
    bx = flat % gx;
    int t = flat / gx;
    by = t % gy;
    bz = t / gy;
}

// ---------------------------------------------------------------------------
// prep: one dispatch for {ebd cast, 3 weight casts, rowsum zero}.
// Flat 1D grid; all ranges are exact multiples of 256 threads x 4 elems.
#define NB_E 24576   // B*S*E/4/256
#define NB_W 576     // E*E/4/256
#define NB_Z 32      // B*S/4/256
__global__ __launch_bounds__(256) void prep(
    const float* __restrict__ ebd, __bf16* __restrict__ ebd_bf,
    const float* __restrict__ wq_f, const float* __restrict__ wk_f,
    const float* __restrict__ wv_f,
    __bf16* __restrict__ wq, __bf16* __restrict__ wk, __bf16* __restrict__ wv,
    float* __restrict__ rowsum) {
    int bid = blockIdx.x;
    if (bid < NB_E) {
        int i = bid * 256 + threadIdx.x;
        float4 v = ((const float4*)ebd)[i];
        bf16x4 o;
        o[0] = (__bf16)v.x; o[1] = (__bf16)v.y; o[2] = (__bf16)v.z; o[3] = (__bf16)v.w;
        ((bf16x4*)ebd_bf)[i] = o;
    } else if (bid < NB_E + 3 * NB_W) {
        int w = (bid - NB_E) / NB_W;
        int i = ((bid - NB_E) % NB_W) * 256 + threadIdx.x;
        const float* in = (w == 0) ? wq_f : (w == 1) ? wk_f : wv_f;
        __bf16* out = (w == 0) ? wq : (w == 1) ? wk : wv;
        float4 v = ((const float4*)in)[i];
        bf16x4 o;
        o[0] = (__bf16)v.x; o[1] = (__bf16)v.y; o[2] = (__bf16)v.z; o[3] = (__bf16)v.w;
        ((bf16x4*)out)[i] = o;
    } else {
        int i = (bid - NB_E - 3 * NB_W) * 256 + threadIdx.x;
        ((f32x4*)rowsum)[i] = f32x4{0.f, 0.f, 0.f, 0.f};
    }
}

// ---------------------------------------------------------------------------
// gemm_bt: C[m][n] = sum_k A[m][k] * Bt[n][k]  (+ bias[n])
// 128x128 tile, BK=64, 256 threads = 4 waves (2x2), wave = 4x4 of 16x16x32 MFMA.
// RESIDENCY-TUNED (R2-proven: 762 TF): __launch_bounds__(256,4) keeps unified
// VGPR+AGPR <= 128/wave -> 4 blocks/CU; inner loop keeps 5 frag regs live.
// Staging: global_load_lds w=16, LDS XOR-swizzled via GLOBAL source index
// (0 bank conflicts measured). swz: T1 XCD remap (requires nwg%8==0).
// EPI: 0 bf16+bias; 1 bf16 transposed+bias; 2 exp2(acc*cs) masked [1,first)
//      + rowsum atomics; 3 fp32 / rowsum.
// exit_mode: 0 none, 1 skip if m0>=first, 2 skip if n0>=first.
// k_mode: 0 K=Kfix, 1 K=roundup64(first).
template <int EPI>
__global__ __launch_bounds__(256, 4) void gemm_bt(
    const __bf16* __restrict__ A, int lda, long strideA,
    const __bf16* __restrict__ B, int ldb, long strideB,
    const float* __restrict__ bias,
    void* __restrict__ Cv, int ldc, long strideC,
    int Kfix, const int* __restrict__ seq, int exit_mode, int k_mode,
    float cs, float* __restrict__ rowsum, int swz) {
    int bx = blockIdx.x, by = blockIdx.y, bz = blockIdx.z;
    if (swz) xcd_swizzle(bx, by, bz);
    int z = bz;
    int m0 = bx * 128, n0 = by * 128;
    int first = seq ? get_first(seq, z) : 0;
    if (exit_mode == 1 && m0 >= first) return;
    if (exit_mode == 2 && n0 >= first) return;
    int K = k_mode ? ((first + 63) & ~63) : Kfix;

    __shared__ char As[16384];
    __shared__ char Bs[16384];

    int tid = threadIdx.x;
    int lane = tid & 63, wid = tid >> 6;
    int waveM = (wid & 1) << 6, waveN = (wid >> 1) << 6;
    int quad = lane >> 4, l16 = lane & 15;

    // staging source: row r0 (+32 per round), swizzled 16B-chunk c8 (round-invariant)
    int r0 = tid >> 3;
    int c8 = (tid & 7) ^ (r0 & 7);
    const __bf16* Ag = A + (long)z * strideA + (long)(m0 + r0) * lda + c8 * 8;
    const __bf16* Bg = B + (long)z * strideB + (long)(n0 + r0) * ldb + c8 * 8;

    f32x4 acc[4][4] = {};
    int xorv = (l16 & 7) << 4;  // frag-read swizzle (byte units)

    for (int k0 = 0; k0 < K; k0 += 64) {
        __syncthreads();  // prior iter's ds_reads done before overwrite
#pragma unroll
        for (int r = 0; r < 4; ++r) {
            async_copy16(Ag + (long)(r * 32) * lda, As + (tid + r * 256) * 16);
            async_copy16(Bg + (long)(r * 32) * ldb, Bs + (tid + r * 256) * 16);
        }
        Ag += 64; Bg += 64;
        __syncthreads();  // drains vmcnt (compiler emits waitcnt before barrier)
#pragma unroll
        for (int s = 0; s < 2; ++s) {
            int chunk = (((s << 2) + quad) << 4) ^ xorv;
            bf16x8 bfr[4];
#pragma unroll
            for (int j = 0; j < 4; ++j)
                bfr[j] = *(const bf16x8*)(Bs + (waveN + j * 16 + l16) * 128 + chunk);
#pragma unroll
            for (int i = 0; i < 4; ++i) {
                bf16x8 af = *(const bf16x8*)(As + (waveM + i * 16 + l16) * 128 + chunk);
#pragma unroll
                for (int j = 0; j < 4; ++j)
                    acc[i][j] = __builtin_amdgcn_mfma_f32_16x16x32_bf16(af, bfr[j], acc[i][j], 0, 0, 0);
            }
        }
    }

    // C/D frag: col = l16 (n), row = quad*4 + reg (m). [m89-verified]
    if (EPI == 0) {
        __bf16* C = (__bf16*)Cv + (long)z * strideC;
#pragma unroll
        for (int i = 0; i < 4; ++i) {
            int rowb = m0 + waveM + i * 16 + quad * 4;
#pragma unroll
            for (int j = 0; j < 4; ++j) {
                int col = n0 + waveN + j * 16 + l16;
                float bv_ = bias[col];
#pragma unroll
                for (int r = 0; r < 4; ++r)
                    C[(long)(rowb + r) * ldc + col] = (__bf16)(acc[i][j][r] + bv_);
            }
        }
    } else if (EPI == 1) {
        __bf16* C = (__bf16*)Cv + (long)z * strideC;
#pragma unroll
        for (int i = 0; i < 4; ++i) {
            int rowb = m0 + waveM + i * 16 + quad * 4;
#pragma unroll
            for (int j = 0; j < 4; ++j) {
                int col = n0 + waveN + j * 16 + l16;
                float bv_ = bias[col];
                bf16x4 o;
#pragma unroll
                for (int r = 0; r < 4; ++r) o[r] = (__bf16)(acc[i][j][r] + bv_);
                *(bf16x4*)&C[(long)col * ldc + rowb] = o;  // rowb%4==0 -> 8B aligned
            }
        }
    } else if (EPI == 2) {
        __bf16* C = (__bf16*)Cv + (long)z * strideC;
        float* rs = rowsum + (long)z * 4096;
#pragma unroll
        for (int i = 0; i < 4; ++i) {
            int rowb = m0 + waveM + i * 16 + quad * 4;
            float sum[4] = {0.f, 0.f, 0.f, 0.f};
#pragma unroll
            for (int j = 0; j < 4; ++j) {
                int col = n0 + waveN + j * 16 + l16;
                bool valid = (col >= 1) && (col < first);
#pragma unroll
                for (int r = 0; r < 4; ++r) {
                    float e = valid ? __builtin_amdgcn_exp2f(acc[i][j][r] * cs) : 0.0f;
                    __bf16 pb = (__bf16)e;
                    C[(long)(rowb + r) * ldc + col] = pb;
                    sum[r] += (float)pb;  // sum the bf16-rounded value (consistent w/ PV)
                }
            }
#pragma unroll
            for (int r = 0; r < 4; ++r) {
                float v = sum[r];
                v += __shfl_xor(v, 8); v += __shfl_xor(v, 4);
                v += __shfl_xor(v, 2); v += __shfl_xor(v, 1);
                if (l16 == 0) atomicAdd(&rs[rowb + r], v);
            }
        }
    } else {
        float* C = (float*)Cv + (long)z * strideC;
        const float* rs = rowsum + (long)z * 4096;
#pragma unroll
        for (int i = 0; i < 4; ++i) {
            int rowb = m0 + waveM + i * 16 + quad * 4;
            float inv[4];
#pragma unroll
            for (int r = 0; r < 4; ++r) inv[r] = 1.0f / rs[rowb + r];
#pragma unroll
            for (int j = 0; j < 4; ++j) {
                int col = n0 + waveN + j * 16 + l16;
#pragma unroll
                for (int r = 0; r < 4; ++r)
                    C[(long)(rowb + r) * ldc + col] = acc[i][j][r] * inv[r];
            }
        }
    }
}

// ---------------------------------------------------------------------------
// gemm_kv: K-proj and V-proj fused in one dispatch. grid.z = 2*B;
// z<B -> K[b] = ebd[b] @ Wk^T + bk (row-major store);
// z>=B -> VT[b] = (ebd[b] @ Wv^T + bv)^T. Same residency-tuned body.
__global__ __launch_bounds__(256, 4) void gemm_kv(
    const __bf16* __restrict__ A, int lda, long strideA,
    const __bf16* __restrict__ Bk, const __bf16* __restrict__ Bv,
    const float* __restrict__ bk, const float* __restrict__ bv,
    __bf16* __restrict__ Ck, __bf16* __restrict__ CvT,
    int Kfix, const int* __restrict__ seq) {
    const int SK = 2048, E = 768;
    int zz = blockIdx.z;
    int isv = (zz >= 8);
    int z = zz & 7;
    int m0 = blockIdx.x * 128, n0 = blockIdx.y * 128;
    int first = get_first(seq, z);
    if (m0 >= first) return;

    __shared__ char As[16384];
    __shared__ char Bs[16384];

    int tid = threadIdx.x;
    int lane = tid & 63, wid = tid >> 6;
    int waveM = (wid & 1) << 6, waveN = (wid >> 1) << 6;
    int quad = lane >> 4, l16 = lane & 15;

    int r0 = tid >> 3;
    int c8 = (tid & 7) ^ (r0 & 7);
    const __bf16* Ag = A + (long)z * strideA + (long)(m0 + r0) * lda + c8 * 8;
    const __bf16* Bm = isv ? Bv : Bk;
    const __bf16* Bg = Bm + (long)(n0 + r0) * lda + c8 * 8;

    f32x4 acc[4][4] = {};
    int xorv = (l16 & 7) << 4;

    for (int k0 = 0; k0 < Kfix; k0 += 64) {
        __syncthreads();
#pragma unroll
        for (int r = 0; r < 4; ++r) {
            async_copy16(Ag + (long)(r * 32) * lda, As + (tid + r * 256) * 16);
            async_copy16(Bg + (long)(r * 32) * lda, Bs + (tid + r * 256) * 16);
        }
        Ag += 64; Bg += 64;
        __syncthreads();
#pragma unroll
        for (int s = 0; s < 2; ++s) {
            int chunk = (((s << 2) + quad) << 4) ^ xorv;
            bf16x8 bfr[4];
#pragma unroll
            for (int j = 0; j < 4; ++j)
                bfr[j] = *(const bf16x8*)(Bs + (waveN + j * 16 + l16) * 128 + chunk);
#pragma unroll
            for (int i = 0; i < 4; ++i) {
                bf16x8 af = *(const bf16x8*)(As + (waveM + i * 16 + l16) * 128 + chunk);
#pragma unroll
                for (int j = 0; j < 4; ++j)
                    acc[i][j] = __builtin_amdgcn_mfma_f32_16x16x32_bf16(af, bfr[j], acc[i][j], 0, 0, 0);
            }
        }
    }

    if (!isv) {
        __bf16* C = Ck + (long)z * SK * E;
        const float* bias = bk;
#pragma unroll
        for (int i = 0; i < 4; ++i) {
            int rowb = m0 + waveM + i * 16 + quad * 4;
#pragma unroll
            for (int j = 0; j < 4; ++j) {
                int col = n0 + waveN + j * 16 + l16;
                float bv_ = bias[col];
#pragma unroll
                for (int r = 0; r < 4; ++r)
                    C[(long)(rowb + r) * E + col] = (__bf16)(acc[i][j][r] + bv_);
            }
        }
    } else {
        __bf16* C = CvT + (long)z * E * SK;
        const float* bias = bv;
#pragma unroll
        for (int i = 0; i < 4; ++i) {
            int rowb = m0 + waveM + i * 16 + quad * 4;
#pragma unroll
            for (int j = 0; j < 4; ++j) {
                int col = n0 + waveN + j * 16 + l16;
                float bv_ = bias[col];
                bf16x4 o;
#pragma unroll
                for (int r = 0; r < 4; ++r) o[r] = (__bf16)(acc[i][j][r] + bv_);
                *(bf16x4*)&C[(long)col * SK + rowb] = o;
            }
        }
    }
}

// ---------------------------------------------------------------------------
extern "C" void kernel_launch(void* const* d_in, const int* in_sizes, int n_in,
                              void* d_out, int out_size, void* d_ws, size_t ws_size,
                              hipStream_t stream) {
    const int B = 8, S = 4096, E = 768, SK = 2048;
    const float* ebd  = (const float*)d_in[0];
    const int*   seq  = (const int*)d_in[1];
    const float* Wq_w = (const float*)d_in[2];
    const float* Wq_b = (const float*)d_in[3];
    const float* Wk_w = (const float*)d_in[4];
    const float* Wk_b = (const float*)d_in[5];
    const float* Wv_w = (const float*)d_in[6];
    const float* Wv_b = (const float*)d_in[7];
    float* out = (float*)d_out;

    char* p = (char*)d_ws;
    __bf16* ebd_bf = (__bf16*)p; p += (size_t)B * S * E * 2;   // 50.3 MB
    __bf16* wq = (__bf16*)p;     p += (size_t)E * E * 2;
    __bf16* wk = (__bf16*)p;     p += (size_t)E * E * 2;
    __bf16* wv = (__bf16*)p;     p += (size_t)E * E * 2;
    __bf16* Qb = (__bf16*)p;     p += (size_t)B * S * E * 2;   // 50.3 MB
    __bf16* Kb = (__bf16*)p;     p += (size_t)B * SK * E * 2;  // 25.2 MB
    __bf16* VT = (__bf16*)p;     p += (size_t)B * E * SK * 2;  // 25.2 MB  V^T: [b][e][k]
    __bf16* Pb = (__bf16*)p;     p += (size_t)B * S * SK * 2;  // 134.2 MB exp-scores
    float* rowsum = (float*)p;   p += (size_t)B * S * 4;       // 128 KB

    // prep: ebd cast + 3 weight casts + rowsum zero, one dispatch
    prep<<<NB_E + 3 * NB_W + NB_Z, 256, 0, stream>>>(
        ebd, ebd_bf, Wq_w, Wk_w, Wv_w, wq, wk, wv, rowsum);

    float cs = (1.0f / sqrtf((float)E)) * 1.44269504088896f;  // scale * log2(e)

    // Q = ebd @ Wq^T + bq  (M = B*S as one GEMM)
    gemm_bt<0><<<dim3(B * S / 128, E / 128, 1), 256, 0, stream>>>(
        ebd_bf, E, 0, wq, E, 0, Wq_b, Qb, E, 0, E, nullptr, 0, 0, 0.f, nullptr, 0);
    // K[b] / VT[b] fused (skip m-tiles >= first)
    gemm_kv<<<dim3(SK / 128, E / 128, 2 * B), 256, 0, stream>>>(
        ebd_bf, E, (long)S * E, wk, wv, Wk_b, Wv_b, Kb, VT, E, seq);
    // P[b] = exp2(Q K^T * cs) masked to [1,first), + rowsum atomics [XCD swz]
    gemm_bt<2><<<dim3(S / 128, SK / 128, B), 256, 0, stream>>>(
        Qb, E, (long)S * E, Kb, E, (long)SK * E, nullptr, Pb, SK, (long)S * SK, E, seq, 2, 0, cs, rowsum, 1);
    // out[b] = (P[b] @ V[b]) / rowsum  (K = roundup64(first)) [XCD swz]
    gemm_bt<3><<<dim3(S / 128, E / 128, B), 256, 0, stream>>>(
        Pb, SK, (long)S * SK, VT, SK, (long)E * SK, nullptr, out, E, (long)S * E, 0, seq, 0, 1, 0.f, rowsum, 1);
}